// Round 7
// baseline (1940.929 us; speedup 1.0000x reference)
//
#include <hip/hip_runtime.h>
#include <hip/hip_bf16.h>
#include <math.h>

#define NNODES 100000
#define NEDGES 3200000
#define BN_EPS 1e-5f
#define NCH 391   // ceil(NNODES/256)

typedef unsigned int uint;
typedef unsigned short ushort;
typedef __attribute__((ext_vector_type(8))) short bf16x8;
typedef __attribute__((ext_vector_type(4))) float f32x4;

__device__ inline float bflo(uint u) { return __uint_as_float(u << 16); }
__device__ inline float bfhi(uint u) { return __uint_as_float(u & 0xffff0000u); }
__device__ inline ushort f2bf(float f) {
    __hip_bfloat16 h = __float2bfloat16(f);
    union { __hip_bfloat16 b; ushort u; } c; c.b = h; return c.u;
}

// ---------------- fused setup: hist | x->bf16 | weight transposes ----------------
// blocks [0,6250): edge histogram (2 edges/thread)
// blocks [6250,18750): x fp32 -> bf16 (4 elems/thread)
// blocks [18750,19310): W1t/W2t/W3t transposed bf16 converts

__global__ void k_setup(const int* __restrict__ edst, int* __restrict__ cnt,
                        const float* __restrict__ x, ushort* __restrict__ xbf16,
                        const float* __restrict__ W1, const float* __restrict__ W2,
                        const float* __restrict__ W3, ushort* __restrict__ W1t,
                        ushort* __restrict__ W2t, ushort* __restrict__ W3t) {
    int b = blockIdx.x;
    if (b < 6250) {
        int e = (b * 256 + threadIdx.x) * 2;
        int2 v = *(const int2*)(edst + e);
        atomicAdd(&cnt[v.x], 1);
        atomicAdd(&cnt[v.y], 1);
    } else if (b < 18750) {
        int i = (b - 6250) * 256 + threadIdx.x;
        float4 v = ((const float4*)x)[i];
        ushort4 o; o.x=f2bf(v.x); o.y=f2bf(v.y); o.z=f2bf(v.z); o.w=f2bf(v.w);
        ((ushort4*)xbf16)[i] = o;
    } else {
        int bb = b - 18750;
        if (bb < 256) {
            for (int k = threadIdx.x; k < 128; k += 256)
                W1t[bb * 128 + k] = f2bf(W1[(size_t)k * 256 + bb]);
        } else if (bb < 512) {
            int n = bb - 256;
            for (int k = threadIdx.x; k < 256; k += 256)
                W2t[n * 256 + k] = f2bf(W2[(size_t)k * 256 + n]);
        } else {
            int n = bb - 512;
            for (int k = threadIdx.x; k < 256; k += 256)
                W3t[n * 256 + k] = (n < 40) ? f2bf(W3[(size_t)k * 40 + n]) : (ushort)0;
        }
    }
}

// dinv + per-chunk sum in one pass
__global__ void k_deg(const int* __restrict__ cnt, float* __restrict__ dinv,
                      int* __restrict__ chunksums) {
    __shared__ int s[256];
    int i = blockIdx.x * 256 + threadIdx.x;
    int c = (i < NNODES) ? cnt[i] : 0;
    if (i < NNODES) dinv[i] = rsqrtf((float)c + 1.0f);   // deg includes self-loop
    s[threadIdx.x] = c;
    __syncthreads();
    for (int o = 128; o > 0; o >>= 1) {
        if (threadIdx.x < o) s[threadIdx.x] += s[threadIdx.x + o];
        __syncthreads();
    }
    if (threadIdx.x == 0) chunksums[blockIdx.x] = s[0];
}

// parallel exclusive scan over NCH chunk sums; writes chunkbase + bucket cursors
__global__ void k_scan1(int* __restrict__ chunksums, int* __restrict__ rowstart,
                        int* __restrict__ bcursor) {
    __shared__ int s[512];
    int t = threadIdx.x;
    int v = (t < NCH) ? chunksums[t] : 0;
    s[t] = v;
    __syncthreads();
    for (int o = 1; o < 512; o <<= 1) {
        int add = (t >= o) ? s[t - o] : 0;
        __syncthreads();
        s[t] += add;
        __syncthreads();
    }
    if (t < NCH) { int ex = s[t] - v; chunksums[t] = ex; bcursor[t] = ex; }
    if (t == NCH - 1) rowstart[NNODES] = s[t];      // total == NEDGES
}

__global__ void k_scan2(const int* __restrict__ cnt, const int* __restrict__ chunkbase,
                        int* __restrict__ rowstart, int* __restrict__ cursor) {
    __shared__ int s[256];
    int t = threadIdx.x;
    int i = blockIdx.x * 256 + t;
    int v = (i < NNODES) ? cnt[i] : 0;
    s[t] = v;
    __syncthreads();
    for (int o = 1; o < 256; o <<= 1) {
        int add = (t >= o) ? s[t - o] : 0;
        __syncthreads();
        s[t] += add;
        __syncthreads();
    }
    if (i < NNODES) {
        int excl = s[t] - v + chunkbase[blockIdx.x];
        rowstart[i] = excl;
        cursor[i]   = excl;
    }
}

// ---------------- two-phase binned scatter ----------------
// Pass A: bin edges by dst-chunk (dst>>8). Bucket-cursor atomics make writes to
// each bucket CONSECUTIVE -> full 64B lines while L2-resident. Pack (src, dst&255)
// into x (src<2^17), w into y.

__global__ void k_scatA(const int* __restrict__ src, const int* __restrict__ dst,
                        const float* __restrict__ dinv, int* __restrict__ bcursor,
                        int2* __restrict__ tmp) {
    int e = (blockIdx.x * 256 + threadIdx.x) * 2;
    int2 ss = *(const int2*)(src + e);
    int2 dd = *(const int2*)(dst + e);
#pragma unroll
    for (int j = 0; j < 2; ++j) {
        int s = j ? ss.y : ss.x, d = j ? dd.y : dd.x;
        int pos = atomicAdd(&bcursor[d >> 8], 1);
        float w = dinv[s] * dinv[d];
        tmp[pos] = make_int2(s | ((d & 255) << 17), __float_as_int(w));
    }
}

// Pass B: per-bucket (2 sub-blocks), scatter into final rows. Row region for a
// bucket spans ~65KB -> L2-resident, writes fill lines.
__global__ void k_scatB(const int* __restrict__ chunkbase, const int2* __restrict__ tmp,
                        int* __restrict__ cursor, int2* __restrict__ pairs) {
    int b = blockIdx.x >> 1, h = blockIdx.x & 1;
    int start = chunkbase[b];
    int end = (b == NCH - 1) ? NEDGES : chunkbase[b + 1];
    int mid = (start + end) >> 1;
    int lo = h ? mid : start, hi = h ? end : mid;
    for (int i = lo + threadIdx.x; i < hi; i += 256) {
        int2 t = tmp[i];
        int s = t.x & 0x1FFFF;
        int d = (b << 8) | (t.x >> 17);
        int pos = atomicAdd(&cursor[d], 1);
        pairs[pos] = make_int2(s, t.y);
    }
}

// ---------------- half-wave bf16 aggregation ----------------

template <int F, int U>
__global__ __launch_bounds__(256) void k_aggh(
    const ushort* __restrict__ X, ushort* __restrict__ Y,
    const int2* __restrict__ pairs, const int* __restrict__ rowstart,
    const float* __restrict__ dinv) {
    constexpr int CPL = F / 32;   // channels per lane: 8 (F=256) or 4 (F=128)
    const int wv = threadIdx.x >> 6;
    const int lane = threadIdx.x & 63;
    const int h = lane >> 5, l32 = lane & 31;
    const int d = blockIdx.x * 4 + wv;          // grid*4 == NNODES exactly
    const int r0 = rowstart[d], r1 = rowstart[d + 1];
    const ushort* Xb = X + (size_t)CPL * l32;
    float acc[CPL] = {};
    int p = r0;
    for (; p + 2 * U <= r1; p += 2 * U) {
        int2 e[U];
#pragma unroll
        for (int j = 0; j < U; ++j) e[j] = pairs[p + 2 * j + h];
        if constexpr (CPL == 8) {
            uint4 u[U];
#pragma unroll
            for (int j = 0; j < U; ++j) u[j] = *(const uint4*)(Xb + (size_t)e[j].x * F);
#pragma unroll
            for (int j = 0; j < U; ++j) {
                float w = __int_as_float(e[j].y);
                acc[0]=fmaf(w,bflo(u[j].x),acc[0]); acc[1]=fmaf(w,bfhi(u[j].x),acc[1]);
                acc[2]=fmaf(w,bflo(u[j].y),acc[2]); acc[3]=fmaf(w,bfhi(u[j].y),acc[3]);
                acc[4]=fmaf(w,bflo(u[j].z),acc[4]); acc[5]=fmaf(w,bfhi(u[j].z),acc[5]);
                acc[6]=fmaf(w,bflo(u[j].w),acc[6]); acc[7]=fmaf(w,bfhi(u[j].w),acc[7]);
            }
        } else {
            uint2 u[U];
#pragma unroll
            for (int j = 0; j < U; ++j) u[j] = *(const uint2*)(Xb + (size_t)e[j].x * F);
#pragma unroll
            for (int j = 0; j < U; ++j) {
                float w = __int_as_float(e[j].y);
                acc[0]=fmaf(w,bflo(u[j].x),acc[0]); acc[1]=fmaf(w,bfhi(u[j].x),acc[1]);
                acc[2]=fmaf(w,bflo(u[j].y),acc[2]); acc[3]=fmaf(w,bfhi(u[j].y),acc[3]);
            }
        }
    }
    for (; p + 2 <= r1; p += 2) {   // paired tail
        int2 e = pairs[p + h];
        float w = __int_as_float(e.y);
        if constexpr (CPL == 8) {
            uint4 u = *(const uint4*)(Xb + (size_t)e.x * F);
            acc[0]=fmaf(w,bflo(u.x),acc[0]); acc[1]=fmaf(w,bfhi(u.x),acc[1]);
            acc[2]=fmaf(w,bflo(u.y),acc[2]); acc[3]=fmaf(w,bfhi(u.y),acc[3]);
            acc[4]=fmaf(w,bflo(u.z),acc[4]); acc[5]=fmaf(w,bfhi(u.z),acc[5]);
            acc[6]=fmaf(w,bflo(u.w),acc[6]); acc[7]=fmaf(w,bfhi(u.w),acc[7]);
        } else {
            uint2 u = *(const uint2*)(Xb + (size_t)e.x * F);
            acc[0]=fmaf(w,bflo(u.x),acc[0]); acc[1]=fmaf(w,bfhi(u.x),acc[1]);
            acc[2]=fmaf(w,bflo(u.y),acc[2]); acc[3]=fmaf(w,bfhi(u.y),acc[3]);
        }
    }
    if (p < r1 && h == 0) {          // odd final edge
        int2 e = pairs[p];
        float w = __int_as_float(e.y);
        if constexpr (CPL == 8) {
            uint4 u = *(const uint4*)(Xb + (size_t)e.x * F);
            acc[0]=fmaf(w,bflo(u.x),acc[0]); acc[1]=fmaf(w,bfhi(u.x),acc[1]);
            acc[2]=fmaf(w,bflo(u.y),acc[2]); acc[3]=fmaf(w,bfhi(u.y),acc[3]);
            acc[4]=fmaf(w,bflo(u.z),acc[4]); acc[5]=fmaf(w,bfhi(u.z),acc[5]);
            acc[6]=fmaf(w,bflo(u.w),acc[6]); acc[7]=fmaf(w,bfhi(u.w),acc[7]);
        } else {
            uint2 u = *(const uint2*)(Xb + (size_t)e.x * F);
            acc[0]=fmaf(w,bflo(u.x),acc[0]); acc[1]=fmaf(w,bfhi(u.x),acc[1]);
            acc[2]=fmaf(w,bflo(u.y),acc[2]); acc[3]=fmaf(w,bfhi(u.y),acc[3]);
        }
    }
#pragma unroll
    for (int c = 0; c < CPL; ++c) acc[c] += __shfl_xor(acc[c], 32);
    if (h == 0) {
        float di = dinv[d], ws = di * di;
        if constexpr (CPL == 8) {
            uint4 u = *(const uint4*)(Xb + (size_t)d * F);
            acc[0]=fmaf(ws,bflo(u.x),acc[0]); acc[1]=fmaf(ws,bfhi(u.x),acc[1]);
            acc[2]=fmaf(ws,bflo(u.y),acc[2]); acc[3]=fmaf(ws,bfhi(u.y),acc[3]);
            acc[4]=fmaf(ws,bflo(u.z),acc[4]); acc[5]=fmaf(ws,bfhi(u.z),acc[5]);
            acc[6]=fmaf(ws,bflo(u.w),acc[6]); acc[7]=fmaf(ws,bfhi(u.w),acc[7]);
            uint4 o;
            o.x = (uint)f2bf(acc[0]) | ((uint)f2bf(acc[1]) << 16);
            o.y = (uint)f2bf(acc[2]) | ((uint)f2bf(acc[3]) << 16);
            o.z = (uint)f2bf(acc[4]) | ((uint)f2bf(acc[5]) << 16);
            o.w = (uint)f2bf(acc[6]) | ((uint)f2bf(acc[7]) << 16);
            *(uint4*)(Y + (size_t)d * F + CPL * l32) = o;
        } else {
            uint2 u = *(const uint2*)(Xb + (size_t)d * F);
            acc[0]=fmaf(ws,bflo(u.x),acc[0]); acc[1]=fmaf(ws,bfhi(u.x),acc[1]);
            acc[2]=fmaf(ws,bflo(u.y),acc[2]); acc[3]=fmaf(ws,bfhi(u.y),acc[3]);
            uint2 o;
            o.x = (uint)f2bf(acc[0]) | ((uint)f2bf(acc[1]) << 16);
            o.y = (uint)f2bf(acc[2]) | ((uint)f2bf(acc[3]) << 16);
            *(uint2*)(Y + (size_t)d * F + CPL * l32) = o;
        }
    }
}

// ---------------- fused 40-wide aggregation + bias + log_softmax ----------------

__global__ __launch_bounds__(256) void k_agg40lsm(
    const ushort* __restrict__ X, float* __restrict__ out,
    const int2* __restrict__ pairs, const int* __restrict__ rowstart,
    const float* __restrict__ dinv, const float* __restrict__ bias) {
    int t = threadIdx.x;
    int wid = t >> 6, lane = t & 63;
    int sub = lane >> 5, l32 = lane & 31;
    int d = blockIdx.x * 8 + wid * 2 + sub;    // 12500*8 == NNODES exactly
    bool act = l32 < 20;
    int col = act ? 2 * l32 : 0;
    const int r0 = rowstart[d], r1 = rowstart[d + 1];
    float a0 = 0.f, a1 = 0.f;
    int p = r0;
    for (; p + 8 <= r1; p += 8) {
        int2 e[8]; uint u[8];
#pragma unroll
        for (int j = 0; j < 8; ++j) e[j] = pairs[p + j];
#pragma unroll
        for (int j = 0; j < 8; ++j) u[j] = *(const uint*)(X + (size_t)e[j].x * 40 + col);
#pragma unroll
        for (int j = 0; j < 8; ++j) {
            float w = __int_as_float(e[j].y);
            a0 = fmaf(w, bflo(u[j]), a0); a1 = fmaf(w, bfhi(u[j]), a1);
        }
    }
    for (; p < r1; ++p) {
        int2 e = pairs[p];
        uint u = *(const uint*)(X + (size_t)e.x * 40 + col);
        float w_ = __int_as_float(e.y);
        a0 = fmaf(w_, bflo(u), a0); a1 = fmaf(w_, bfhi(u), a1);
    }
    float di = dinv[d], ws = di * di;
    uint us = *(const uint*)(X + (size_t)d * 40 + col);
    a0 = fmaf(ws, bflo(us), a0); a1 = fmaf(ws, bfhi(us), a1);
    if (act) { a0 += bias[col]; a1 += bias[col + 1]; }
    else     { a0 = -INFINITY;  a1 = -INFINITY; }
    float mx = fmaxf(a0, a1);
    for (int o = 16; o > 0; o >>= 1) mx = fmaxf(mx, __shfl_xor(mx, o, 32));
    float e = act ? (expf(a0 - mx) + expf(a1 - mx)) : 0.f;
    float s = e;
    for (int o = 16; o > 0; o >>= 1) s += __shfl_xor(s, o, 32);
    float ls = logf(s);
    if (act)
        *(float2*)(out + (size_t)d * 40 + col) = make_float2(a0 - mx - ls, a1 - mx - ls);
}

// ---------------- MFMA GEMM: C[M x 256](bf16) = A[M x K](bf16) @ Bt[256 x K]^T ----------------
// BNA: fused BN+ReLU on A during staging (scale/shift computed in LDS from sums).
// STATS: per-channel sum/sumsq of f32 C into sums_out.

__device__ inline bf16x8 bnrelu8(bf16x8 v, const float* scsh, int ch) {
    bf16x8 r;
#pragma unroll
    for (int j = 0; j < 8; ++j) {
        float f = __uint_as_float(((uint)(ushort)v[j]) << 16);
        f = fmaxf(fmaf(f, scsh[ch + j], scsh[256 + ch + j]), 0.f);
        r[j] = (short)f2bf(f);
    }
    return r;
}

template <int K, bool BNA, bool STATS>
__global__ __launch_bounds__(256) void k_gmm(
    const ushort* __restrict__ A, const ushort* __restrict__ Bt,
    const float* __restrict__ bsums, const float* __restrict__ g,
    const float* __restrict__ be, ushort* __restrict__ C,
    float* __restrict__ sums_out) {
    __shared__ ushort As[128 * 32];
    __shared__ ushort Bs[128 * 32];
    __shared__ float scsh[512];
    if constexpr (BNA) {   // inline bnfin: 256 threads, one channel each
        int c = threadIdx.x;
        float mean = bsums[c] * (1.0f / NNODES);
        float var  = bsums[256 + c] * (1.0f / NNODES) - mean * mean;
        float sc = g[c] * rsqrtf(var + BN_EPS);
        scsh[c] = sc;
        scsh[256 + c] = be[c] - mean * sc;
        __syncthreads();
    }
    const int m0 = blockIdx.x * 128;
    const int n0 = blockIdx.y * 128;
    const int tid = threadIdx.x;
    const int lane = tid & 63;
    const int wid = tid >> 6;
    const int wr = wid >> 1, wc = wid & 1;
    const int sr1 = tid >> 2, sc_ = tid & 3;
    const int sr2 = sr1 + 64;
    const int ssl1 = sr1 * 32 + ((sc_ ^ ((sr1 >> 1) & 3)) * 8);
    const int ssl2 = sr2 * 32 + ((sc_ ^ ((sr2 >> 1) & 3)) * 8);
    const size_t ga1 = (size_t)min(m0 + sr1, NNODES - 1) * K + sc_ * 8;
    const size_t ga2 = (size_t)min(m0 + sr2, NNODES - 1) * K + sc_ * 8;
    const size_t gb1 = (size_t)(n0 + sr1) * K + sc_ * 8;
    const size_t gb2 = (size_t)(n0 + sr2) * K + sc_ * 8;
    const int kc = lane >> 4, rr = lane & 15;
    f32x4 acc[4][4] = {};
    for (int k0 = 0; k0 < K; k0 += 32) {
        bf16x8 av1 = *(const bf16x8*)(A + ga1 + k0);
        bf16x8 av2 = *(const bf16x8*)(A + ga2 + k0);
        bf16x8 bv1 = *(const bf16x8*)(Bt + gb1 + k0);
        bf16x8 bv2 = *(const bf16x8*)(Bt + gb2 + k0);
        if constexpr (BNA) {
            int ch = k0 + sc_ * 8;
            av1 = bnrelu8(av1, scsh, ch);
            av2 = bnrelu8(av2, scsh, ch);
        }
        if (k0) __syncthreads();
        *(bf16x8*)(As + ssl1) = av1;
        *(bf16x8*)(As + ssl2) = av2;
        *(bf16x8*)(Bs + ssl1) = bv1;
        *(bf16x8*)(Bs + ssl2) = bv2;
        __syncthreads();
        bf16x8 af[4], bfr[4];
#pragma unroll
        for (int f = 0; f < 4; ++f) {
            int ar = wr * 64 + f * 16 + rr;
            int br = wc * 64 + f * 16 + rr;
            af[f]  = *(const bf16x8*)(As + ar * 32 + ((kc ^ ((ar >> 1) & 3)) * 8));
            bfr[f] = *(const bf16x8*)(Bs + br * 32 + ((kc ^ ((br >> 1) & 3)) * 8));
        }
#pragma unroll
        for (int fm = 0; fm < 4; ++fm)
#pragma unroll
            for (int fn = 0; fn < 4; ++fn)
                acc[fm][fn] = __builtin_amdgcn_mfma_f32_16x16x32_bf16(af[fm], bfr[fn], acc[fm][fn], 0, 0, 0);
    }
    const int crow0 = m0 + wr * 64 + (lane >> 4) * 4;
    const int ccol0 = n0 + wc * 64 + (lane & 15);
#pragma unroll
    for (int fm = 0; fm < 4; ++fm) {
#pragma unroll
        for (int r = 0; r < 4; ++r) {
            int m = crow0 + fm * 16 + r;
            if (m >= NNODES) continue;
#pragma unroll
            for (int fn = 0; fn < 4; ++fn)
                C[(size_t)m * 256 + ccol0 + fn * 16] = f2bf(acc[fm][fn][r]);
        }
    }
    if constexpr (STATS) {
#pragma unroll
        for (int fn = 0; fn < 4; ++fn) {
            float s = 0.f, s2 = 0.f;
#pragma unroll
            for (int fm = 0; fm < 4; ++fm)
#pragma unroll
                for (int r = 0; r < 4; ++r) {
                    int m = crow0 + fm * 16 + r;
                    if (m < NNODES) { float v = acc[fm][fn][r]; s += v; s2 += v * v; }
                }
            s  += __shfl_xor(s, 16);  s  += __shfl_xor(s, 32);
            s2 += __shfl_xor(s2, 16); s2 += __shfl_xor(s2, 32);
            if (lane < 16) {
                int ch = ccol0 + fn * 16;
                atomicAdd(&sums_out[ch], s);
                atomicAdd(&sums_out[256 + ch], s2);
            }
        }
    }
}

// ---------------- MFMA GEMM3: C[M x 40](bf16) = relu(bn(A))[M x 256] @ W3t[48 x 256]^T ----
// BN scale/shift computed in LDS from sums (inline bnfin).

__global__ __launch_bounds__(256) void k_gmm3m(
    const ushort* __restrict__ A, const ushort* __restrict__ Bt,
    const float* __restrict__ bsums, const float* __restrict__ g,
    const float* __restrict__ be, ushort* __restrict__ C) {
    __shared__ ushort As[128 * 64];
    __shared__ ushort Bs[48 * 64];
    __shared__ float scsh[512];
    {
        int c = threadIdx.x;
        float mean = bsums[c] * (1.0f / NNODES);
        float var  = bsums[256 + c] * (1.0f / NNODES) - mean * mean;
        float sc = g[c] * rsqrtf(var + BN_EPS);
        scsh[c] = sc;
        scsh[256 + c] = be[c] - mean * sc;
        __syncthreads();
    }
    const int m0 = blockIdx.x * 128;
    const int tid = threadIdx.x;
    const int lane = tid & 63;
    const int wm = tid >> 6;
    const int kc = lane >> 4, rr = lane & 15;
    f32x4 acc[2][3] = {};
    for (int k0 = 0; k0 < 256; k0 += 64) {
        bf16x8 avs[4];
        int arow[4], ach[4];
#pragma unroll
        for (int i = 0; i < 4; ++i) {
            int c = i * 256 + tid;
            arow[i] = c >> 3; ach[i] = c & 7;
            int m = min(m0 + arow[i], NNODES - 1);
            bf16x8 v = *(const bf16x8*)(A + (size_t)m * 256 + k0 + ach[i] * 8);
            avs[i] = bnrelu8(v, scsh, k0 + ach[i] * 8);
        }
        bf16x8 bvs[2];
#pragma unroll
        for (int i = 0; i < 2; ++i) {
            int c = i * 256 + tid;
            if (c < 384) {
                int row = c >> 3, ch = c & 7;
                bvs[i] = *(const bf16x8*)(Bt + (size_t)row * 256 + k0 + ch * 8);
            }
        }
        if (k0) __syncthreads();
#pragma unroll
        for (int i = 0; i < 4; ++i)
            *(bf16x8*)(As + arow[i] * 64 + ((ach[i] ^ (arow[i] & 7)) * 8)) = avs[i];
#pragma unroll
        for (int i = 0; i < 2; ++i) {
            int c = i * 256 + tid;
            if (c < 384) {
                int row = c >> 3, ch = c & 7;
                *(bf16x8*)(Bs + row * 64 + ((ch ^ (row & 7)) * 8)) = bvs[i];
            }
        }
        __syncthreads();
#pragma unroll
        for (int ks = 0; ks < 2; ++ks) {
            bf16x8 af[2], bfm[3];
#pragma unroll
            for (int fm = 0; fm < 2; ++fm) {
                int ar = wm * 32 + fm * 16 + rr;
                af[fm] = *(const bf16x8*)(As + ar * 64 + (((ks * 4 + kc) ^ (ar & 7)) * 8));
            }
#pragma unroll
            for (int fn = 0; fn < 3; ++fn) {
                int br = fn * 16 + rr;
                bfm[fn] = *(const bf16x8*)(Bs + br * 64 + (((ks * 4 + kc) ^ (br & 7)) * 8));
            }
#pragma unroll
            for (int fm = 0; fm < 2; ++fm)
#pragma unroll
                for (int fn = 0; fn < 3; ++fn)
                    acc[fm][fn] = __builtin_amdgcn_mfma_f32_16x16x32_bf16(af[fm], bfm[fn], acc[fm][fn], 0, 0, 0);
        }
    }
    const int crow0 = m0 + wm * 32 + (lane >> 4) * 4;
    const int ccol = lane & 15;
#pragma unroll
    for (int fm = 0; fm < 2; ++fm)
#pragma unroll
        for (int r = 0; r < 4; ++r) {
            int m = crow0 + fm * 16 + r;
            if (m >= NNODES) continue;
#pragma unroll
            for (int fn = 0; fn < 3; ++fn) {
                int col = fn * 16 + ccol;
                if (col < 40) C[(size_t)m * 40 + col] = f2bf(acc[fm][fn][r]);
            }
        }
}

// ---------------- BatchNorm stats (bf16 input) ----------------

__global__ void k_bnstats_bf(const uint* __restrict__ H, float* __restrict__ sums) {
    int t = threadIdx.x;
    int pp = t & 127, half = t >> 7;
    size_t row0 = (size_t)blockIdx.x * 256 + half * 128;
    float s0=0, s20=0, s1=0, s21=0;
    for (int i = 0; i < 128; ++i) {
        size_t m = row0 + i;
        if (m >= NNODES) break;
        uint u = H[m * 128 + pp];
        float v0 = bflo(u), v1 = bfhi(u);
        s0 += v0; s20 += v0*v0; s1 += v1; s21 += v1*v1;
    }
    atomicAdd(&sums[2*pp],       s0);
    atomicAdd(&sums[2*pp+1],     s1);
    atomicAdd(&sums[256+2*pp],   s20);
    atomicAdd(&sums[256+2*pp+1], s21);
}

// ---------------- launch ----------------

extern "C" void kernel_launch(void* const* d_in, const int* in_sizes, int n_in,
                              void* d_out, int out_size, void* d_ws, size_t ws_size,
                              hipStream_t stream) {
    const float* x  = (const float*)d_in[0];
    const int*   ei = (const int*)d_in[1];
    const float* W1 = (const float*)d_in[2];
    const float* W2 = (const float*)d_in[4];
    const float* W3 = (const float*)d_in[6];
    const float* b3 = (const float*)d_in[7];
    const float* g1 = (const float*)d_in[8];
    const float* be1 = (const float*)d_in[9];
    const float* g2 = (const float*)d_in[10];
    const float* be2 = (const float*)d_in[11];
    float* out = (float*)d_out;
    // b1, b2 cancel exactly through BatchNorm (per-channel shift); dropped.

    const int* esrc = ei;
    const int* edst = ei + NEDGES;

    char* p = (char*)d_ws;
    auto alloc = [&](size_t bytes) { char* r = p; p += (bytes + 511) & ~(size_t)511; return r; };
    float* dinv     = (float*)alloc((size_t)NNODES * 4);
    int*   cnt      = (int*)  alloc((size_t)NNODES * 4);
    int*   rowstart = (int*)  alloc((size_t)(NNODES + 1) * 4);
    int*   cursor   = (int*)  alloc((size_t)NNODES * 4);
    int*   chunksums= (int*)  alloc((size_t)NCH * 4);
    int*   bcursor  = (int*)  alloc((size_t)NCH * 4);
    float* stats    = (float*)alloc((size_t)2048 * 4);
    ushort* W1t     = (ushort*)alloc((size_t)256 * 128 * 2);
    ushort* W2t     = (ushort*)alloc((size_t)256 * 256 * 2);
    ushort* W3t     = (ushort*)alloc((size_t)48 * 256 * 2);
    int2*  pairs    = (int2*) alloc((size_t)NEDGES * 8);
    char*  R1       = alloc((size_t)NNODES * 256 * 2);   // 51.2 MB
    char*  R2       = alloc((size_t)NNODES * 256 * 2);   // 51.2 MB
    char*  R3       = alloc((size_t)NNODES * 256 * 2);   // 51.2 MB

    // R1: xbf16 [0,25.6M) + P_bf [25.6M,51.2M); after gmm128 both dead -> t3_bf
    ushort* xbf16 = (ushort*)R1;
    ushort* P_bf  = (ushort*)R1 + (size_t)NNODES * 128;
    ushort* t3_bf = (ushort*)R1;
    // R2: h1_bf (written by gmm128, read by gmm256); then h2_bf (aggh256 out)
    ushort* h1_bf = (ushort*)R2;
    ushort* h2_bf = (ushort*)R2;
    // R3: scatter tmp (binned edges, dead after scatB); then t_bf (gmm256 out)
    int2*   tmp   = (int2*)R3;
    ushort* t_bf  = (ushort*)R3;

    float* sums1 = stats;
    float* sums2 = stats + 1024;

    hipMemsetAsync(cnt, 0, (size_t)NNODES * 4, stream);
    hipMemsetAsync(stats, 0, (size_t)2048 * 4, stream);

    // setup: hist + x->bf16 + weight converts (one kernel, block-ranged)
    k_setup<<<19310, 256, 0, stream>>>(edst, cnt, x, xbf16, W1, W2, W3, W1t, W2t, W3t);
    k_deg<<<NCH, 256, 0, stream>>>(cnt, dinv, chunksums);
    k_scan1<<<1, 512, 0, stream>>>(chunksums, rowstart, bcursor);
    k_scan2<<<NCH, 256, 0, stream>>>(cnt, chunksums, rowstart, cursor);
    k_scatA<<<NEDGES / 512, 256, 0, stream>>>(esrc, edst, dinv, bcursor, tmp);
    k_scatB<<<NCH * 2, 256, 0, stream>>>(chunksums, tmp, cursor, pairs);

    dim3 ggrid((NNODES + 127) / 128, 2);

    // Layer 1: P = Agg(x); h1 = P@W1 (stats fused into epilogue)
    k_aggh<128, 8><<<NNODES / 4, 256, 0, stream>>>(xbf16, P_bf, pairs, rowstart, dinv);
    k_gmm<128, false, true><<<ggrid, 256, 0, stream>>>(P_bf, W1t, nullptr, nullptr, nullptr, h1_bf, sums1);

    // Layer 2: t = relu(bn(h1))@W2 (bnfin inline); h2 = Agg(t); stats(h2)
    k_gmm<256, true, false><<<ggrid, 256, 0, stream>>>(h1_bf, W2t, sums1, g1, be1, t_bf, nullptr);
    k_aggh<256, 8><<<NNODES / 4, 256, 0, stream>>>(t_bf, h2_bf, pairs, rowstart, dinv);
    k_bnstats_bf<<<NCH, 256, 0, stream>>>((const uint*)h2_bf, sums2);

    // Layer 3: t3 = relu(bn(h2))@W3 (MFMA, bnfin inline); out = log_softmax(Agg(t3)+b3)
    k_gmm3m<<<(NNODES + 127) / 128, 256, 0, stream>>>(h2_bf, W3t, sums2, g2, be2, t3_bf);
    k_agg40lsm<<<NNODES / 8, 256, 0, stream>>>(t3_bf, out, pairs, rowstart, dinv, b3);
}

// Round 8
// 906.812 us; speedup vs baseline: 2.1404x; 2.1404x over previous
//
#include <hip/hip_runtime.h>
#include <hip/hip_bf16.h>
#include <math.h>

#define NNODES 100000
#define NEDGES 3200000
#define BN_EPS 1e-5f
#define NCH 391   // ceil(NNODES/256)

typedef unsigned int uint;
typedef unsigned short ushort;
typedef __attribute__((ext_vector_type(8))) short bf16x8;
typedef __attribute__((ext_vector_type(4))) float f32x4;

__device__ inline float bflo(uint u) { return __uint_as_float(u << 16); }
__device__ inline float bfhi(uint u) { return __uint_as_float(u & 0xffff0000u); }
__device__ inline ushort f2bf(float f) {
    __hip_bfloat16 h = __float2bfloat16(f);
    union { __hip_bfloat16 b; ushort u; } c; c.b = h; return c.u;
}

// ---------------- fused setup: hist | x->bf16 | weight transposes ----------------

__global__ void k_setup(const int* __restrict__ edst, int* __restrict__ cnt,
                        const float* __restrict__ x, ushort* __restrict__ xbf16,
                        const float* __restrict__ W1, const float* __restrict__ W2,
                        const float* __restrict__ W3, ushort* __restrict__ W1t,
                        ushort* __restrict__ W2t, ushort* __restrict__ W3t) {
    int b = blockIdx.x;
    if (b < 6250) {
        int e = (b * 256 + threadIdx.x) * 2;
        int2 v = *(const int2*)(edst + e);
        atomicAdd(&cnt[v.x], 1);
        atomicAdd(&cnt[v.y], 1);
    } else if (b < 18750) {
        int i = (b - 6250) * 256 + threadIdx.x;
        float4 v = ((const float4*)x)[i];
        ushort4 o; o.x=f2bf(v.x); o.y=f2bf(v.y); o.z=f2bf(v.z); o.w=f2bf(v.w);
        ((ushort4*)xbf16)[i] = o;
    } else {
        int bb = b - 18750;
        if (bb < 256) {
            for (int k = threadIdx.x; k < 128; k += 256)
                W1t[bb * 128 + k] = f2bf(W1[(size_t)k * 256 + bb]);
        } else if (bb < 512) {
            int n = bb - 256;
            for (int k = threadIdx.x; k < 256; k += 256)
                W2t[n * 256 + k] = f2bf(W2[(size_t)k * 256 + n]);
        } else {
            int n = bb - 512;
            for (int k = threadIdx.x; k < 256; k += 256)
                W3t[n * 256 + k] = (n < 40) ? f2bf(W3[(size_t)k * 40 + n]) : (ushort)0;
        }
    }
}

// dinv + per-chunk sum in one pass
__global__ void k_deg(const int* __restrict__ cnt, float* __restrict__ dinv,
                      int* __restrict__ chunksums) {
    __shared__ int s[256];
    int i = blockIdx.x * 256 + threadIdx.x;
    int c = (i < NNODES) ? cnt[i] : 0;
    if (i < NNODES) dinv[i] = rsqrtf((float)c + 1.0f);   // deg includes self-loop
    s[threadIdx.x] = c;
    __syncthreads();
    for (int o = 128; o > 0; o >>= 1) {
        if (threadIdx.x < o) s[threadIdx.x] += s[threadIdx.x + o];
        __syncthreads();
    }
    if (threadIdx.x == 0) chunksums[blockIdx.x] = s[0];
}

// parallel exclusive scan over NCH chunk sums
__global__ void k_scan1(int* __restrict__ chunksums, int* __restrict__ rowstart) {
    __shared__ int s[512];
    int t = threadIdx.x;
    int v = (t < NCH) ? chunksums[t] : 0;
    s[t] = v;
    __syncthreads();
    for (int o = 1; o < 512; o <<= 1) {
        int add = (t >= o) ? s[t - o] : 0;
        __syncthreads();
        s[t] += add;
        __syncthreads();
    }
    if (t < NCH) chunksums[t] = s[t] - v;           // exclusive
    if (t == NCH - 1) rowstart[NNODES] = s[t];      // total == NEDGES
}

__global__ void k_scan2(const int* __restrict__ cnt, const int* __restrict__ chunkbase,
                        int* __restrict__ rowstart, int* __restrict__ cursor) {
    __shared__ int s[256];
    int t = threadIdx.x;
    int i = blockIdx.x * 256 + t;
    int v = (i < NNODES) ? cnt[i] : 0;
    s[t] = v;
    __syncthreads();
    for (int o = 1; o < 256; o <<= 1) {
        int add = (t >= o) ? s[t - o] : 0;
        __syncthreads();
        s[t] += add;
        __syncthreads();
    }
    if (i < NNODES) {
        int excl = s[t] - v + chunkbase[blockIdx.x];
        rowstart[i] = excl;
        cursor[i]   = excl;
    }
}

// direct scatter: 3.2M atomics spread over 100K cursor addresses (low contention).
// NOTE (R7 lesson): binning by 391 bucket cursors serialized on ~25 cache lines
// and cost 1100 µs. Contention scales with atomics-per-line, not write locality.
__global__ void k_scatter(const int* __restrict__ src, const int* __restrict__ dst,
                          const float* __restrict__ dinv, int* __restrict__ cursor,
                          int2* __restrict__ pairs) {
    int e = blockIdx.x * 256 + threadIdx.x;
    if (e >= NEDGES) return;
    int s = src[e], d = dst[e];
    int p = atomicAdd(&cursor[d], 1);
    float w = dinv[s] * dinv[d];
    pairs[p] = make_int2(s, __float_as_int(w));
}

// ---------------- half-wave bf16 aggregation ----------------

template <int F, int U>
__global__ __launch_bounds__(256) void k_aggh(
    const ushort* __restrict__ X, ushort* __restrict__ Y,
    const int2* __restrict__ pairs, const int* __restrict__ rowstart,
    const float* __restrict__ dinv) {
    constexpr int CPL = F / 32;   // channels per lane: 8 (F=256) or 4 (F=128)
    const int wv = threadIdx.x >> 6;
    const int lane = threadIdx.x & 63;
    const int h = lane >> 5, l32 = lane & 31;
    const int d = blockIdx.x * 4 + wv;          // grid*4 == NNODES exactly
    const int r0 = rowstart[d], r1 = rowstart[d + 1];
    const ushort* Xb = X + (size_t)CPL * l32;
    float acc[CPL] = {};
    int p = r0;
    for (; p + 2 * U <= r1; p += 2 * U) {
        int2 e[U];
#pragma unroll
        for (int j = 0; j < U; ++j) e[j] = pairs[p + 2 * j + h];
        if constexpr (CPL == 8) {
            uint4 u[U];
#pragma unroll
            for (int j = 0; j < U; ++j) u[j] = *(const uint4*)(Xb + (size_t)e[j].x * F);
#pragma unroll
            for (int j = 0; j < U; ++j) {
                float w = __int_as_float(e[j].y);
                acc[0]=fmaf(w,bflo(u[j].x),acc[0]); acc[1]=fmaf(w,bfhi(u[j].x),acc[1]);
                acc[2]=fmaf(w,bflo(u[j].y),acc[2]); acc[3]=fmaf(w,bfhi(u[j].y),acc[3]);
                acc[4]=fmaf(w,bflo(u[j].z),acc[4]); acc[5]=fmaf(w,bfhi(u[j].z),acc[5]);
                acc[6]=fmaf(w,bflo(u[j].w),acc[6]); acc[7]=fmaf(w,bfhi(u[j].w),acc[7]);
            }
        } else {
            uint2 u[U];
#pragma unroll
            for (int j = 0; j < U; ++j) u[j] = *(const uint2*)(Xb + (size_t)e[j].x * F);
#pragma unroll
            for (int j = 0; j < U; ++j) {
                float w = __int_as_float(e[j].y);
                acc[0]=fmaf(w,bflo(u[j].x),acc[0]); acc[1]=fmaf(w,bfhi(u[j].x),acc[1]);
                acc[2]=fmaf(w,bflo(u[j].y),acc[2]); acc[3]=fmaf(w,bfhi(u[j].y),acc[3]);
            }
        }
    }
    for (; p + 2 <= r1; p += 2) {   // paired tail
        int2 e = pairs[p + h];
        float w = __int_as_float(e.y);
        if constexpr (CPL == 8) {
            uint4 u = *(const uint4*)(Xb + (size_t)e.x * F);
            acc[0]=fmaf(w,bflo(u.x),acc[0]); acc[1]=fmaf(w,bfhi(u.x),acc[1]);
            acc[2]=fmaf(w,bflo(u.y),acc[2]); acc[3]=fmaf(w,bfhi(u.y),acc[3]);
            acc[4]=fmaf(w,bflo(u.z),acc[4]); acc[5]=fmaf(w,bfhi(u.z),acc[5]);
            acc[6]=fmaf(w,bflo(u.w),acc[6]); acc[7]=fmaf(w,bfhi(u.w),acc[7]);
        } else {
            uint2 u = *(const uint2*)(Xb + (size_t)e.x * F);
            acc[0]=fmaf(w,bflo(u.x),acc[0]); acc[1]=fmaf(w,bfhi(u.x),acc[1]);
            acc[2]=fmaf(w,bflo(u.y),acc[2]); acc[3]=fmaf(w,bfhi(u.y),acc[3]);
        }
    }
    if (p < r1 && h == 0) {          // odd final edge
        int2 e = pairs[p];
        float w = __int_as_float(e.y);
        if constexpr (CPL == 8) {
            uint4 u = *(const uint4*)(Xb + (size_t)e.x * F);
            acc[0]=fmaf(w,bflo(u.x),acc[0]); acc[1]=fmaf(w,bfhi(u.x),acc[1]);
            acc[2]=fmaf(w,bflo(u.y),acc[2]); acc[3]=fmaf(w,bfhi(u.y),acc[3]);
            acc[4]=fmaf(w,bflo(u.z),acc[4]); acc[5]=fmaf(w,bfhi(u.z),acc[5]);
            acc[6]=fmaf(w,bflo(u.w),acc[6]); acc[7]=fmaf(w,bfhi(u.w),acc[7]);
        } else {
            uint2 u = *(const uint2*)(Xb + (size_t)e.x * F);
            acc[0]=fmaf(w,bflo(u.x),acc[0]); acc[1]=fmaf(w,bfhi(u.x),acc[1]);
            acc[2]=fmaf(w,bflo(u.y),acc[2]); acc[3]=fmaf(w,bfhi(u.y),acc[3]);
        }
    }
#pragma unroll
    for (int c = 0; c < CPL; ++c) acc[c] += __shfl_xor(acc[c], 32);
    if (h == 0) {
        float di = dinv[d], ws = di * di;
        if constexpr (CPL == 8) {
            uint4 u = *(const uint4*)(Xb + (size_t)d * F);
            acc[0]=fmaf(ws,bflo(u.x),acc[0]); acc[1]=fmaf(ws,bfhi(u.x),acc[1]);
            acc[2]=fmaf(ws,bflo(u.y),acc[2]); acc[3]=fmaf(ws,bfhi(u.y),acc[3]);
            acc[4]=fmaf(ws,bflo(u.z),acc[4]); acc[5]=fmaf(ws,bfhi(u.z),acc[5]);
            acc[6]=fmaf(ws,bflo(u.w),acc[6]); acc[7]=fmaf(ws,bfhi(u.w),acc[7]);
            uint4 o;
            o.x = (uint)f2bf(acc[0]) | ((uint)f2bf(acc[1]) << 16);
            o.y = (uint)f2bf(acc[2]) | ((uint)f2bf(acc[3]) << 16);
            o.z = (uint)f2bf(acc[4]) | ((uint)f2bf(acc[5]) << 16);
            o.w = (uint)f2bf(acc[6]) | ((uint)f2bf(acc[7]) << 16);
            *(uint4*)(Y + (size_t)d * F + CPL * l32) = o;
        } else {
            uint2 u = *(const uint2*)(Xb + (size_t)d * F);
            acc[0]=fmaf(ws,bflo(u.x),acc[0]); acc[1]=fmaf(ws,bfhi(u.x),acc[1]);
            acc[2]=fmaf(ws,bflo(u.y),acc[2]); acc[3]=fmaf(ws,bfhi(u.y),acc[3]);
            uint2 o;
            o.x = (uint)f2bf(acc[0]) | ((uint)f2bf(acc[1]) << 16);
            o.y = (uint)f2bf(acc[2]) | ((uint)f2bf(acc[3]) << 16);
            *(uint2*)(Y + (size_t)d * F + CPL * l32) = o;
        }
    }
}

// ---------------- fused 40-wide aggregation + bias + log_softmax ----------------

__global__ __launch_bounds__(256) void k_agg40lsm(
    const ushort* __restrict__ X, float* __restrict__ out,
    const int2* __restrict__ pairs, const int* __restrict__ rowstart,
    const float* __restrict__ dinv, const float* __restrict__ bias) {
    int t = threadIdx.x;
    int wid = t >> 6, lane = t & 63;
    int sub = lane >> 5, l32 = lane & 31;
    int d = blockIdx.x * 8 + wid * 2 + sub;    // 12500*8 == NNODES exactly
    bool act = l32 < 20;
    int col = act ? 2 * l32 : 0;
    const int r0 = rowstart[d], r1 = rowstart[d + 1];
    float a0 = 0.f, a1 = 0.f;
    int p = r0;
    for (; p + 8 <= r1; p += 8) {
        int2 e[8]; uint u[8];
#pragma unroll
        for (int j = 0; j < 8; ++j) e[j] = pairs[p + j];
#pragma unroll
        for (int j = 0; j < 8; ++j) u[j] = *(const uint*)(X + (size_t)e[j].x * 40 + col);
#pragma unroll
        for (int j = 0; j < 8; ++j) {
            float w = __int_as_float(e[j].y);
            a0 = fmaf(w, bflo(u[j]), a0); a1 = fmaf(w, bfhi(u[j]), a1);
        }
    }
    for (; p < r1; ++p) {
        int2 e = pairs[p];
        uint u = *(const uint*)(X + (size_t)e.x * 40 + col);
        float w_ = __int_as_float(e.y);
        a0 = fmaf(w_, bflo(u), a0); a1 = fmaf(w_, bfhi(u), a1);
    }
    float di = dinv[d], ws = di * di;
    uint us = *(const uint*)(X + (size_t)d * 40 + col);
    a0 = fmaf(ws, bflo(us), a0); a1 = fmaf(ws, bfhi(us), a1);
    if (act) { a0 += bias[col]; a1 += bias[col + 1]; }
    else     { a0 = -INFINITY;  a1 = -INFINITY; }
    float mx = fmaxf(a0, a1);
    for (int o = 16; o > 0; o >>= 1) mx = fmaxf(mx, __shfl_xor(mx, o, 32));
    float e = act ? (expf(a0 - mx) + expf(a1 - mx)) : 0.f;
    float s = e;
    for (int o = 16; o > 0; o >>= 1) s += __shfl_xor(s, o, 32);
    float ls = logf(s);
    if (act)
        *(float2*)(out + (size_t)d * 40 + col) = make_float2(a0 - mx - ls, a1 - mx - ls);
}

// ---------------- MFMA GEMM: C[M x 256](bf16) = A[M x K](bf16) @ Bt[256 x K]^T ----------------

__device__ inline bf16x8 bnrelu8(bf16x8 v, const float* scsh, int ch) {
    bf16x8 r;
#pragma unroll
    for (int j = 0; j < 8; ++j) {
        float f = __uint_as_float(((uint)(ushort)v[j]) << 16);
        f = fmaxf(fmaf(f, scsh[ch + j], scsh[256 + ch + j]), 0.f);
        r[j] = (short)f2bf(f);
    }
    return r;
}

template <int K, bool BNA, bool STATS>
__global__ __launch_bounds__(256) void k_gmm(
    const ushort* __restrict__ A, const ushort* __restrict__ Bt,
    const float* __restrict__ bsums, const float* __restrict__ g,
    const float* __restrict__ be, ushort* __restrict__ C,
    float* __restrict__ sums_out) {
    __shared__ ushort As[128 * 32];
    __shared__ ushort Bs[128 * 32];
    __shared__ float scsh[512];
    if constexpr (BNA) {   // inline bnfin
        int c = threadIdx.x;
        float mean = bsums[c] * (1.0f / NNODES);
        float var  = bsums[256 + c] * (1.0f / NNODES) - mean * mean;
        float sc = g[c] * rsqrtf(var + BN_EPS);
        scsh[c] = sc;
        scsh[256 + c] = be[c] - mean * sc;
        __syncthreads();
    }
    const int m0 = blockIdx.x * 128;
    const int n0 = blockIdx.y * 128;
    const int tid = threadIdx.x;
    const int lane = tid & 63;
    const int wid = tid >> 6;
    const int wr = wid >> 1, wc = wid & 1;
    const int sr1 = tid >> 2, sc_ = tid & 3;
    const int sr2 = sr1 + 64;
    const int ssl1 = sr1 * 32 + ((sc_ ^ ((sr1 >> 1) & 3)) * 8);
    const int ssl2 = sr2 * 32 + ((sc_ ^ ((sr2 >> 1) & 3)) * 8);
    const size_t ga1 = (size_t)min(m0 + sr1, NNODES - 1) * K + sc_ * 8;
    const size_t ga2 = (size_t)min(m0 + sr2, NNODES - 1) * K + sc_ * 8;
    const size_t gb1 = (size_t)(n0 + sr1) * K + sc_ * 8;
    const size_t gb2 = (size_t)(n0 + sr2) * K + sc_ * 8;
    const int kc = lane >> 4, rr = lane & 15;
    f32x4 acc[4][4] = {};
    for (int k0 = 0; k0 < K; k0 += 32) {
        bf16x8 av1 = *(const bf16x8*)(A + ga1 + k0);
        bf16x8 av2 = *(const bf16x8*)(A + ga2 + k0);
        bf16x8 bv1 = *(const bf16x8*)(Bt + gb1 + k0);
        bf16x8 bv2 = *(const bf16x8*)(Bt + gb2 + k0);
        if constexpr (BNA) {
            int ch = k0 + sc_ * 8;
            av1 = bnrelu8(av1, scsh, ch);
            av2 = bnrelu8(av2, scsh, ch);
        }
        if (k0) __syncthreads();
        *(bf16x8*)(As + ssl1) = av1;
        *(bf16x8*)(As + ssl2) = av2;
        *(bf16x8*)(Bs + ssl1) = bv1;
        *(bf16x8*)(Bs + ssl2) = bv2;
        __syncthreads();
        bf16x8 af[4], bfr[4];
#pragma unroll
        for (int f = 0; f < 4; ++f) {
            int ar = wr * 64 + f * 16 + rr;
            int br = wc * 64 + f * 16 + rr;
            af[f]  = *(const bf16x8*)(As + ar * 32 + ((kc ^ ((ar >> 1) & 3)) * 8));
            bfr[f] = *(const bf16x8*)(Bs + br * 32 + ((kc ^ ((br >> 1) & 3)) * 8));
        }
#pragma unroll
        for (int fm = 0; fm < 4; ++fm)
#pragma unroll
            for (int fn = 0; fn < 4; ++fn)
                acc[fm][fn] = __builtin_amdgcn_mfma_f32_16x16x32_bf16(af[fm], bfr[fn], acc[fm][fn], 0, 0, 0);
    }
    const int crow0 = m0 + wr * 64 + (lane >> 4) * 4;
    const int ccol0 = n0 + wc * 64 + (lane & 15);
#pragma unroll
    for (int fm = 0; fm < 4; ++fm) {
#pragma unroll
        for (int r = 0; r < 4; ++r) {
            int m = crow0 + fm * 16 + r;
            if (m >= NNODES) continue;
#pragma unroll
            for (int fn = 0; fn < 4; ++fn)
                C[(size_t)m * 256 + ccol0 + fn * 16] = f2bf(acc[fm][fn][r]);
        }
    }
    if constexpr (STATS) {
#pragma unroll
        for (int fn = 0; fn < 4; ++fn) {
            float s = 0.f, s2 = 0.f;
#pragma unroll
            for (int fm = 0; fm < 4; ++fm)
#pragma unroll
                for (int r = 0; r < 4; ++r) {
                    int m = crow0 + fm * 16 + r;
                    if (m < NNODES) { float v = acc[fm][fn][r]; s += v; s2 += v * v; }
                }
            s  += __shfl_xor(s, 16);  s  += __shfl_xor(s, 32);
            s2 += __shfl_xor(s2, 16); s2 += __shfl_xor(s2, 32);
            if (lane < 16) {
                int ch = ccol0 + fn * 16;
                atomicAdd(&sums_out[ch], s);
                atomicAdd(&sums_out[256 + ch], s2);
            }
        }
    }
}

// ---------------- MFMA GEMM3: C[M x 40](bf16) = relu(bn(A))[M x 256] @ W3t[48 x 256]^T ----

__global__ __launch_bounds__(256) void k_gmm3m(
    const ushort* __restrict__ A, const ushort* __restrict__ Bt,
    const float* __restrict__ bsums, const float* __restrict__ g,
    const float* __restrict__ be, ushort* __restrict__ C) {
    __shared__ ushort As[128 * 64];
    __shared__ ushort Bs[48 * 64];
    __shared__ float scsh[512];
    {
        int c = threadIdx.x;
        float mean = bsums[c] * (1.0f / NNODES);
        float var  = bsums[256 + c] * (1.0f / NNODES) - mean * mean;
        float sc = g[c] * rsqrtf(var + BN_EPS);
        scsh[c] = sc;
        scsh[256 + c] = be[c] - mean * sc;
        __syncthreads();
    }
    const int m0 = blockIdx.x * 128;
    const int tid = threadIdx.x;
    const int lane = tid & 63;
    const int wm = tid >> 6;
    const int kc = lane >> 4, rr = lane & 15;
    f32x4 acc[2][3] = {};
    for (int k0 = 0; k0 < 256; k0 += 64) {
        bf16x8 avs[4];
        int arow[4], ach[4];
#pragma unroll
        for (int i = 0; i < 4; ++i) {
            int c = i * 256 + tid;
            arow[i] = c >> 3; ach[i] = c & 7;
            int m = min(m0 + arow[i], NNODES - 1);
            bf16x8 v = *(const bf16x8*)(A + (size_t)m * 256 + k0 + ach[i] * 8);
            avs[i] = bnrelu8(v, scsh, k0 + ach[i] * 8);
        }
        bf16x8 bvs[2];
#pragma unroll
        for (int i = 0; i < 2; ++i) {
            int c = i * 256 + tid;
            if (c < 384) {
                int row = c >> 3, ch = c & 7;
                bvs[i] = *(const bf16x8*)(Bt + (size_t)row * 256 + k0 + ch * 8);
            }
        }
        if (k0) __syncthreads();
#pragma unroll
        for (int i = 0; i < 4; ++i)
            *(bf16x8*)(As + arow[i] * 64 + ((ach[i] ^ (arow[i] & 7)) * 8)) = avs[i];
#pragma unroll
        for (int i = 0; i < 2; ++i) {
            int c = i * 256 + tid;
            if (c < 384) {
                int row = c >> 3, ch = c & 7;
                *(bf16x8*)(Bs + row * 64 + ((ch ^ (row & 7)) * 8)) = bvs[i];
            }
        }
        __syncthreads();
#pragma unroll
        for (int ks = 0; ks < 2; ++ks) {
            bf16x8 af[2], bfm[3];
#pragma unroll
            for (int fm = 0; fm < 2; ++fm) {
                int ar = wm * 32 + fm * 16 + rr;
                af[fm] = *(const bf16x8*)(As + ar * 64 + (((ks * 4 + kc) ^ (ar & 7)) * 8));
            }
#pragma unroll
            for (int fn = 0; fn < 3; ++fn) {
                int br = fn * 16 + rr;
                bfm[fn] = *(const bf16x8*)(Bs + br * 64 + (((ks * 4 + kc) ^ (br & 7)) * 8));
            }
#pragma unroll
            for (int fm = 0; fm < 2; ++fm)
#pragma unroll
                for (int fn = 0; fn < 3; ++fn)
                    acc[fm][fn] = __builtin_amdgcn_mfma_f32_16x16x32_bf16(af[fm], bfm[fn], acc[fm][fn], 0, 0, 0);
        }
    }
    const int crow0 = m0 + wm * 32 + (lane >> 4) * 4;
    const int ccol = lane & 15;
#pragma unroll
    for (int fm = 0; fm < 2; ++fm)
#pragma unroll
        for (int r = 0; r < 4; ++r) {
            int m = crow0 + fm * 16 + r;
            if (m >= NNODES) continue;
#pragma unroll
            for (int fn = 0; fn < 3; ++fn) {
                int col = fn * 16 + ccol;
                if (col < 40) C[(size_t)m * 40 + col] = f2bf(acc[fm][fn][r]);
            }
        }
}

// ---------------- BatchNorm stats (bf16 input) ----------------

__global__ void k_bnstats_bf(const uint* __restrict__ H, float* __restrict__ sums) {
    int t = threadIdx.x;
    int pp = t & 127, half = t >> 7;
    size_t row0 = (size_t)blockIdx.x * 256 + half * 128;
    float s0=0, s20=0, s1=0, s21=0;
    for (int i = 0; i < 128; ++i) {
        size_t m = row0 + i;
        if (m >= NNODES) break;
        uint u = H[m * 128 + pp];
        float v0 = bflo(u), v1 = bfhi(u);
        s0 += v0; s20 += v0*v0; s1 += v1; s21 += v1*v1;
    }
    atomicAdd(&sums[2*pp],       s0);
    atomicAdd(&sums[2*pp+1],     s1);
    atomicAdd(&sums[256+2*pp],   s20);
    atomicAdd(&sums[256+2*pp+1], s21);
}

// ---------------- launch ----------------

extern "C" void kernel_launch(void* const* d_in, const int* in_sizes, int n_in,
                              void* d_out, int out_size, void* d_ws, size_t ws_size,
                              hipStream_t stream) {
    const float* x  = (const float*)d_in[0];
    const int*   ei = (const int*)d_in[1];
    const float* W1 = (const float*)d_in[2];
    const float* W2 = (const float*)d_in[4];
    const float* W3 = (const float*)d_in[6];
    const float* b3 = (const float*)d_in[7];
    const float* g1 = (const float*)d_in[8];
    const float* be1 = (const float*)d_in[9];
    const float* g2 = (const float*)d_in[10];
    const float* be2 = (const float*)d_in[11];
    float* out = (float*)d_out;
    // b1, b2 cancel exactly through BatchNorm (per-channel shift); dropped.

    const int* esrc = ei;
    const int* edst = ei + NEDGES;

    char* p = (char*)d_ws;
    auto alloc = [&](size_t bytes) { char* r = p; p += (bytes + 511) & ~(size_t)511; return r; };
    float* dinv     = (float*)alloc((size_t)NNODES * 4);
    int*   cnt      = (int*)  alloc((size_t)NNODES * 4);
    int*   rowstart = (int*)  alloc((size_t)(NNODES + 1) * 4);
    int*   cursor   = (int*)  alloc((size_t)NNODES * 4);
    int*   chunksums= (int*)  alloc((size_t)NCH * 4);
    float* stats    = (float*)alloc((size_t)2048 * 4);
    ushort* W1t     = (ushort*)alloc((size_t)256 * 128 * 2);
    ushort* W2t     = (ushort*)alloc((size_t)256 * 256 * 2);
    ushort* W3t     = (ushort*)alloc((size_t)48 * 256 * 2);
    int2*  pairs    = (int2*) alloc((size_t)NEDGES * 8);
    char*  R1       = alloc((size_t)NNODES * 256 * 2);   // 51.2 MB
    char*  R2       = alloc((size_t)NNODES * 256 * 2);   // 51.2 MB
    char*  R3       = alloc((size_t)NNODES * 256 * 2);   // 51.2 MB

    // R1: xbf16 [0,25.6M) + P_bf [25.6M,51.2M); after gmm128 both dead -> t3_bf
    ushort* xbf16 = (ushort*)R1;
    ushort* P_bf  = (ushort*)R1 + (size_t)NNODES * 128;
    ushort* t3_bf = (ushort*)R1;
    // R2: h1_bf (written by gmm128, read by gmm256); then h2_bf (aggh256 out)
    ushort* h1_bf = (ushort*)R2;
    ushort* h2_bf = (ushort*)R2;
    // R3: t_bf (gmm256 out; distinct from h1_bf, blocks re-read A rows)
    ushort* t_bf  = (ushort*)R3;

    float* sums1 = stats;
    float* sums2 = stats + 1024;

    hipMemsetAsync(cnt, 0, (size_t)NNODES * 4, stream);
    hipMemsetAsync(stats, 0, (size_t)2048 * 4, stream);

    // setup: hist + x->bf16 + weight converts
    k_setup<<<19310, 256, 0, stream>>>(edst, cnt, x, xbf16, W1, W2, W3, W1t, W2t, W3t);
    k_deg<<<NCH, 256, 0, stream>>>(cnt, dinv, chunksums);
    k_scan1<<<1, 512, 0, stream>>>(chunksums, rowstart);
    k_scan2<<<NCH, 256, 0, stream>>>(cnt, chunksums, rowstart, cursor);
    k_scatter<<<NEDGES / 256, 256, 0, stream>>>(esrc, edst, dinv, cursor, pairs);

    dim3 ggrid((NNODES + 127) / 128, 2);

    // Layer 1: P = Agg(x); h1 = P@W1 (stats fused into epilogue)
    k_aggh<128, 8><<<NNODES / 4, 256, 0, stream>>>(xbf16, P_bf, pairs, rowstart, dinv);
    k_gmm<128, false, true><<<ggrid, 256, 0, stream>>>(P_bf, W1t, nullptr, nullptr, nullptr, h1_bf, sums1);

    // Layer 2: t = relu(bn(h1))@W2 (bnfin inline); h2 = Agg(t); stats(h2)
    k_gmm<256, true, false><<<ggrid, 256, 0, stream>>>(h1_bf, W2t, sums1, g1, be1, t_bf, nullptr);
    k_aggh<256, 8><<<NNODES / 4, 256, 0, stream>>>(t_bf, h2_bf, pairs, rowstart, dinv);
    k_bnstats_bf<<<NCH, 256, 0, stream>>>((const uint*)h2_bf, sums2);

    // Layer 3: t3 = relu(bn(h2))@W3 (MFMA, bnfin inline); out = log_softmax(Agg(t3)+b3)
    k_gmm3m<<<(NNODES + 127) / 128, 256, 0, stream>>>(h2_bf, W3t, sums2, g2, be2, t3_bf);
    k_agg40lsm<<<NNODES / 8, 256, 0, stream>>>(t3_bf, out, pairs, rowstart, dinv, b3);
}